// Round 10
// baseline (534.573 us; speedup 1.0000x reference)
//
#include <hip/hip_runtime.h>
#include <hip/hip_bf16.h>
#include <hip/hip_cooperative_groups.h>

namespace cg = cooperative_groups;

typedef __bf16 bf16_t;
typedef __bf16 bf16x8 __attribute__((ext_vector_type(8)));
typedef __bf16 bf16x4 __attribute__((ext_vector_type(4)));
typedef float f32x4 __attribute__((ext_vector_type(4)));
typedef unsigned int u32;
typedef const __attribute__((address_space(1))) u32* gptr_t;
typedef __attribute__((address_space(3))) u32* lptr_t;

static constexpr int Bb = 16, Ss = 1024, Hh = 768;

// ---- per-batch mask compaction: tok[b][j] = j-th valid s, cnt[b] = count ----
__global__ __launch_bounds__(256) void compact_mask(
    const int* __restrict__ mask, int* __restrict__ tok, int* __restrict__ cnt)
{
    const int b = blockIdx.x;
    const int t = threadIdx.x;
    const int4 m4 = *(const int4*)&mask[(b << 10) + (t << 2)];
    const int c = (m4.x != 0) + (m4.y != 0) + (m4.z != 0) + (m4.w != 0);
    __shared__ int sb[256];
    sb[t] = c;
    __syncthreads();
    for (int off = 1; off < 256; off <<= 1) {
        int v = (t >= off) ? sb[t - off] : 0;
        __syncthreads();
        sb[t] += v;
        __syncthreads();
    }
    int p = sb[t] - c;  // exclusive prefix
    int* tb = tok + (b << 10);
    if (m4.x) tb[p++] = (t << 2) + 0;
    if (m4.y) tb[p++] = (t << 2) + 1;
    if (m4.z) tb[p++] = (t << 2) + 2;
    if (m4.w) tb[p++] = (t << 2) + 3;
    if (t == 255) cnt[b] = sb[255];
}

// ---- conversions + cvec: weights -> bf16 slab, bias pack, x gather-convert,
// ---- and cvec = W2·relu(b1)+b2 (coalesced block-parallel reduction) ----
__global__ __launch_bounds__(256) void cvt_all(
    const float* __restrict__ x,
    const float* __restrict__ w0, const float* __restrict__ w1,
    const float* __restrict__ w2, const float* __restrict__ w3,
    const float* __restrict__ w4,
    const float* __restrict__ bq, const float* __restrict__ bk,
    const float* __restrict__ bv,
    const float* __restrict__ b1, const float* __restrict__ b2,
    const int* __restrict__ tok, const int* __restrict__ cnt,
    bf16_t* __restrict__ xc, bf16_t* __restrict__ wdst, float* __restrict__ bdst,
    float* __restrict__ cvec)
{
    const int bx = blockIdx.x;
    const int t = threadIdx.x;
    if (bx < 2880) {
        int seg = bx / 576;
        const float* src = seg == 0 ? w0 : seg == 1 ? w1 : seg == 2 ? w2 : seg == 3 ? w3 : w4;
        int i = (bx % 576) * 256 + t;
        float4 v = ((const float4*)src)[i];
        bf16x4 o = { (bf16_t)v.x, (bf16_t)v.y, (bf16_t)v.z, (bf16_t)v.w };
        ((bf16x4*)(wdst + (long)seg * 589824))[i] = o;
    } else if (bx < 2889) {
        int i = (bx - 2880) * 256 + t;
        if (i < 2304)
            bdst[i] = i < 768 ? bq[i] : i < 1536 ? bk[i - 768] : bv[i - 1536];
    } else if (bx < 19273) {
        const int idx = bx - 2889;
        const int b = idx >> 10, j = idx & 1023;
        if (j < cnt[b] && t < 192) {
            const int s = tok[(b << 10) + j];
            float4 v = ((const float4*)(x + ((long)((b << 10) + s)) * 768))[t];
            bf16x4 o = { (bf16_t)v.x, (bf16_t)v.y, (bf16_t)v.z, (bf16_t)v.w };
            ((bf16x4*)(xc + ((long)((b << 10) + j)) * 768))[t] = o;
        }
    } else {
        // cvec: 96 blocks x 8 outputs; 32 lanes reduce one W2 row (coalesced)
        const int o = ((bx - 19273) << 3) + (t >> 5);
        const int l = t & 31;
        const float* wr = w4 + (long)o * 768;
        float acc = 0.f;
        for (int h = l; h < 768; h += 32) acc += wr[h] * fmaxf(b1[h], 0.f);
#pragma unroll
        for (int off = 16; off; off >>= 1) acc += __shfl_down(acc, off, 32);
        if (l == 0) cvec[o] = acc + b2[o];
    }
}

// ---------------- async global->LDS 16B ----------------
__device__ __forceinline__ void async_cp16(const void* g, void* l)
{
    __builtin_amdgcn_global_load_lds((gptr_t)g, (lptr_t)l, 16, 0, 0);
}

enum { EG_QKV = 0, EG_SCORE_C = 1, EG_PV = 2, EG_FFN1 = 3, EG_FFN2 = 4 };

#define SBAR __builtin_amdgcn_s_barrier()
#define VMW(n) asm volatile("s_waitcnt vmcnt(" #n ")" ::: "memory")

static constexpr int TSZ = 128 * 64;   // elements per LDS tile buffer (16 KB)

// One GEMM phase of the fused chain. C = epi(A * B^T); 128x128 tile, BK=64,
// 8 waves, per-wave 32x64 (wm=wid&3, wn=wid>>2), MI=2 NI=4. Ring-2 LDS;
// stage(t+1) at top of iter t; VMW(0)+s_barrier per iter. LDS [128][64] per
// tile, 16B-chunk XOR swizzle chunk^=(row&7); source pre-swizzled (rule 21).
// Persistent-block work loop over dense active tiles; SBAR at tile top
// protects LDS reuse (prev tile's ds_reads consumed before its waves pass).
template <int EPI, int NT>
__device__ void gemm_phase(
    bf16_t* Asl, bf16_t* Bsl,
    const bf16_t* __restrict__ A, const bf16_t* __restrict__ B,
    const float* __restrict__ bias, const bf16_t* __restrict__ resid,
    const int* __restrict__ tok, const int* __restrict__ cnt,
    void* __restrict__ Cout, bf16_t* __restrict__ out2, bf16_t* __restrict__ out3,
    int K, int lda, int ldb, long sA, long sB, float scale)
{
    int tot = 0;
#pragma unroll
    for (int b = 0; b < 16; b++) {
        int a = (cnt[b] + 127) >> 7;
        tot += (EPI == EG_SCORE_C) ? a * a : a * NT;
    }

    constexpr int MI = 2, NI = 4;
    const int tid = threadIdx.x;
    const int wid = tid >> 6;     // 0..7
    const int lane = tid & 63;
    const int wm = wid & 3, wn = wid >> 2;
    const int srow8 = lane >> 3;
    const int scg = ((lane & 7) ^ srow8) << 3;
    const int wrow = wid << 4;
    const int arow = lane & 15;
    const int axr = lane & 7;
    const int f0 = (arow << 6) + (((lane >> 4)      ^ axr) << 3);
    const int f1 = (arow << 6) + ((((lane >> 4) + 4) ^ axr) << 3);
    const int colw = lane & 15;
    const int rowq = (lane >> 4) << 2;

    for (int w = blockIdx.x; w < tot; w += gridDim.x) {
        // decode w -> (bz, mi, ni) by per-batch walk
        int wv = w, bz = 0;
        for (;;) {
            int a = (cnt[bz] + 127) >> 7;
            int t = (EPI == EG_SCORE_C) ? a * a : a * NT;
            if (wv < t) break;
            wv -= t; ++bz;
        }
        int mi, ni;
        if constexpr (EPI == EG_SCORE_C) {
            int a = (cnt[bz] + 127) >> 7;
            mi = wv / a; ni = wv - mi * a;
        } else {
            mi = wv / NT; ni = wv - mi * NT;
        }
        const int cb = cnt[bz];
        const int m0 = mi << 7;
        const int n0 = ni << 7;
        const int Kend = (EPI == EG_PV) ? ((cb + 63) & ~63) : K;
        const int nk = Kend >> 6;

        const bf16_t* Ab = A + (long)bz * sA;
        const bf16_t* Bp = B + (long)bz * sB;
        const bf16_t* pa[2];
        const bf16_t* pb[2];
#pragma unroll
        for (int qq = 0; qq < 2; qq++) {
            pa[qq] = Ab + (long)(m0 + (wid << 4) + (qq << 3) + srow8) * lda + scg;
            pb[qq] = Bp + (long)(n0 + (wid << 4) + (qq << 3) + srow8) * ldb + scg;
        }

        auto stage = [&](int tk, int buf) {
            const long ko = (long)tk << 6;
#pragma unroll
            for (int qq = 0; qq < 2; qq++) {
                async_cp16(pa[qq] + ko, &Asl[buf * TSZ + ((wrow + (qq << 3)) << 6)]);
                async_cp16(pb[qq] + ko, &Bsl[buf * TSZ + ((wrow + (qq << 3)) << 6)]);
            }
        };

        f32x4 acc[MI][NI] = {};

        SBAR;   // LDS safe: all waves' prior-tile ds_reads consumed
        stage(0, 0);
        __builtin_amdgcn_sched_barrier(0);
        VMW(0); SBAR;

        for (int t = 0; t < nk; ++t) {
            if (t + 1 < nk) stage(t + 1, (t + 1) & 1);

            const int cba = (t & 1) * TSZ;
            bf16x8 af[MI][2], bfr[NI][2];
#pragma unroll
            for (int i = 0; i < MI; i++) {
                const int rb = cba + ((wm * MI + i) << 10);
                af[i][0] = *(const bf16x8*)&Asl[rb + f0];
                af[i][1] = *(const bf16x8*)&Asl[rb + f1];
            }
#pragma unroll
            for (int j = 0; j < NI; j++) {
                const int rb = cba + ((wn * NI + j) << 10);
                bfr[j][0] = *(const bf16x8*)&Bsl[rb + f0];
                bfr[j][1] = *(const bf16x8*)&Bsl[rb + f1];
            }
            __builtin_amdgcn_sched_barrier(0);
#pragma unroll
            for (int kk = 0; kk < 2; kk++)
#pragma unroll
                for (int i = 0; i < MI; i++)
#pragma unroll
                    for (int j = 0; j < NI; j++)
                        acc[i][j] = __builtin_amdgcn_mfma_f32_16x16x32_bf16(
                            af[i][kk], bfr[j][kk], acc[i][j], 0, 0, 0);
            __builtin_amdgcn_sched_barrier(0);
            if (t + 1 < nk) { VMW(0); SBAR; }
        }

        // epilogue — C/D per 16x16 tile: col = lane&15, row = (lane>>4)*4 + reg
        const int mb_ = m0 + wm * 32;
        const int nb_ = n0 + wn * 64;

        if constexpr (EPI == EG_QKV) {
            float bj[NI];
#pragma unroll
            for (int j = 0; j < NI; j++) bj[j] = bias[nb_ + (j << 4) + colw];
            if (nb_ < 1536) {
                bf16_t* C = ((nb_ < 768) ? (bf16_t*)Cout : out2) + (long)bz * 786432;
                const int cbase = (nb_ < 768) ? nb_ : nb_ - 768;
#pragma unroll
                for (int i = 0; i < MI; i++)
#pragma unroll
                    for (int j = 0; j < NI; j++)
#pragma unroll
                        for (int r2 = 0; r2 < 4; r2++) {
                            int row = mb_ + (i << 4) + rowq + r2;
                            int col = cbase + (j << 4) + colw;
                            C[(long)row * Hh + col] = (bf16_t)fmaxf(acc[i][j][r2] + bj[j], 0.f);
                        }
            } else {
                bf16_t* C = out3 + (long)bz * 786432;  // vTc[b][h][jc]
#pragma unroll
                for (int i = 0; i < MI; i++) {
                    const int jc0 = mb_ + (i << 4) + rowq;
#pragma unroll
                    for (int j = 0; j < NI; j++) {
                        const int col = nb_ - 1536 + (j << 4) + colw;
                        bf16x4 o = { (bf16_t)(acc[i][j][0] + bj[j]), (bf16_t)(acc[i][j][1] + bj[j]),
                                     (bf16_t)(acc[i][j][2] + bj[j]), (bf16_t)(acc[i][j][3] + bj[j]) };
                        *(bf16x4*)&C[(long)col * 1024 + jc0] = o;
                    }
                }
            }
        } else if constexpr (EPI == EG_SCORE_C) {
            bf16_t* C = (bf16_t*)Cout + (long)bz * 1048576;
#pragma unroll
            for (int i = 0; i < MI; i++) {
                const int kbase = mb_ + (i << 4) + rowq;
#pragma unroll
                for (int j = 0; j < NI; j++) {
                    const int qrow = nb_ + (j << 4) + colw;
                    bf16x4 o = { (bf16_t)(acc[i][j][0] * scale), (bf16_t)(acc[i][j][1] * scale),
                                 (bf16_t)(acc[i][j][2] * scale), (bf16_t)(acc[i][j][3] * scale) };
                    *(bf16x4*)&C[(long)qrow * 1024 + kbase] = o;
                }
            }
        } else if constexpr (EPI == EG_FFN2) {
            float* outp = (float*)Cout;
            const bf16_t* crow = resid + (long)bz * 786432;
            const int* tb = tok + (bz << 10);
            float bj[NI];
#pragma unroll
            for (int j = 0; j < NI; j++) bj[j] = bias[nb_ + (j << 4) + colw];
#pragma unroll
            for (int i = 0; i < MI; i++)
#pragma unroll
                for (int r2 = 0; r2 < 4; r2++) {
                    const int jq = mb_ + (i << 4) + rowq + r2;
                    if (jq < cb) {
                        const int s = tb[jq];
                        float* orow = outp + ((long)((bz << 10) + s)) * 768;
                        const bf16_t* cr = crow + (long)jq * 768;
#pragma unroll
                        for (int j = 0; j < NI; j++) {
                            const int col = nb_ + (j << 4) + colw;
                            orow[col] = acc[i][j][r2] + bj[j] + (float)cr[col];
                        }
                    }
                }
        } else {
            // EG_PV (plain bf16) / EG_FFN1 (relu+bias bf16), compact per-batch
            bf16_t* C = (bf16_t*)Cout + (long)bz * 786432;
            float bj[NI];
#pragma unroll
            for (int j = 0; j < NI; j++) bj[j] = 0.f;
            if constexpr (EPI == EG_FFN1) {
#pragma unroll
                for (int j = 0; j < NI; j++) bj[j] = bias[nb_ + (j << 4) + colw];
            }
#pragma unroll
            for (int i = 0; i < MI; i++)
#pragma unroll
                for (int j = 0; j < NI; j++)
#pragma unroll
                    for (int r2 = 0; r2 < 4; r2++) {
                        int row = mb_ + (i << 4) + rowq + r2;
                        int col = nb_ + (j << 4) + colw;
                        float val = acc[i][j][r2] + bj[j];
                        if constexpr (EPI == EG_FFN1) val = fmaxf(val, 0.f);
                        C[(long)row * Hh + col] = (bf16_t)val;
                    }
        }
    }
}

// wave-per-row softmax over compact keys + cvec fill for masked-out rows.
// No LDS, no block barriers: 64-lane shuffle reductions only.
__device__ void softmax_phase(
    bf16_t* __restrict__ S_, const int* __restrict__ cnt,
    const int* __restrict__ mask, const float* __restrict__ cvec,
    float* __restrict__ out)
{
    const int wid = threadIdx.x >> 6, lane = threadIdx.x & 63;
    const int gw = blockIdx.x * 8 + wid;
    const int nw = gridDim.x << 3;

    for (int rw = gw; rw < 16384; rw += nw) {
        const int b = rw >> 10, jq = rw & 1023;
        const int cb = cnt[b];
        if (jq < cb) {
            bf16_t* p = S_ + (((long)(b << 10)) + jq) * 1024;
            const int c0 = lane << 4;
            bf16x8 u = *(const bf16x8*)&p[c0];
            bf16x8 v = *(const bf16x8*)&p[c0 + 8];
            float f[16];
#pragma unroll
            for (int i = 0; i < 8; i++) {
                f[i]     = (c0 + i     < cb) ? (float)u[i] : -1e30f;
                f[8 + i] = (c0 + 8 + i < cb) ? (float)v[i] : -1e30f;
            }
            float mx = f[0];
#pragma unroll
            for (int i = 1; i < 16; i++) mx = fmaxf(mx, f[i]);
#pragma unroll
            for (int off = 32; off; off >>= 1) mx = fmaxf(mx, __shfl_xor(mx, off, 64));
            float sm = 0.f;
#pragma unroll
            for (int i = 0; i < 16; i++) { f[i] = __expf(f[i] - mx); sm += f[i]; }
#pragma unroll
            for (int off = 32; off; off >>= 1) sm += __shfl_xor(sm, off, 64);
            const float inv = 1.f / sm;
            bf16x8 o0, o1;
#pragma unroll
            for (int i = 0; i < 8; i++) {
                o0[i] = (bf16_t)(f[i] * inv);
                o1[i] = (bf16_t)(f[8 + i] * inv);
            }
            *(bf16x8*)&p[c0] = o0;
            *(bf16x8*)&p[c0 + 8] = o1;
        }
    }
    // masked-out output rows = cvec (disjoint from FFN2's rows)
    for (int rw = gw; rw < 16384; rw += nw) {
        const int b = rw >> 10, s = rw & 1023;
        if (!mask[(b << 10) + s]) {
            float* orow = out + ((long)((b << 10) + s)) * 768;
#pragma unroll
            for (int i = 0; i < 3; i++)
                ((float4*)orow)[(i << 6) + lane] = ((const float4*)cvec)[(i << 6) + lane];
        }
    }
}

struct KParams {
    const bf16_t *xc, *wqkv, *w1b, *w2b;
    const float *bqkv, *b1, *b2, *cvec;
    bf16_t *qc, *kc, *vTc, *sc, *ctxc, *h1c;
    const int *tok, *cnt, *mask;
    float *out;
    float inv_sqrt_h;
};

// Persistent cooperative kernel: the whole dependent chain in ONE launch.
// Phases separated by grid.sync() (device-scope coherence). Aliases safe:
// ctxc(=xc) written in PV, xc last read in QKV (2 syncs prior); h1c(=qc)
// written in FFN1, qc last read in score. sc rows >= cnt carry finite
// garbage (never consumed downstream) — same invariant as the split kernels.
__global__ __launch_bounds__(512, 4) void fused_chain(KParams p)
{
    __shared__ __align__(16) bf16_t Asl[2 * TSZ];
    __shared__ __align__(16) bf16_t Bsl[2 * TSZ];
    cg::grid_group grid = cg::this_grid();

    gemm_phase<EG_QKV, 18>(Asl, Bsl, p.xc, p.wqkv, p.bqkv, nullptr, p.tok, p.cnt,
                           p.qc, p.kc, p.vTc, 768, 768, 768, 786432, 0, 1.f);
    grid.sync();
    gemm_phase<EG_SCORE_C, 1>(Asl, Bsl, p.kc, p.qc, nullptr, nullptr, p.tok, p.cnt,
                              p.sc, nullptr, nullptr, 768, 768, 768, 786432, 786432,
                              p.inv_sqrt_h);
    grid.sync();
    softmax_phase(p.sc, p.cnt, p.mask, p.cvec, p.out);
    grid.sync();
    gemm_phase<EG_PV, 6>(Asl, Bsl, p.sc, p.vTc, nullptr, nullptr, p.tok, p.cnt,
                         p.ctxc, nullptr, nullptr, 0, 1024, 1024, 1048576, 786432, 1.f);
    grid.sync();
    gemm_phase<EG_FFN1, 6>(Asl, Bsl, p.ctxc, p.w1b, p.b1, nullptr, p.tok, p.cnt,
                           p.h1c, nullptr, nullptr, 768, 768, 768, 786432, 0, 1.f);
    grid.sync();
    gemm_phase<EG_FFN2, 6>(Asl, Bsl, p.h1c, p.w2b, p.b2, p.ctxc, p.tok, p.cnt,
                           p.out, nullptr, nullptr, 768, 768, 768, 786432, 0, 1.f);
}

extern "C" void kernel_launch(void* const* d_in, const int* in_sizes, int n_in,
                              void* d_out, int out_size, void* d_ws, size_t ws_size,
                              hipStream_t stream)
{
    const float* x  = (const float*)d_in[0];
    const int* mask = (const int*)d_in[1];
    const float* Wq = (const float*)d_in[2];
    const float* bq = (const float*)d_in[3];
    const float* Wk = (const float*)d_in[4];
    const float* bk = (const float*)d_in[5];
    const float* Wv = (const float*)d_in[6];
    const float* bv = (const float*)d_in[7];
    const float* W1 = (const float*)d_in[8];
    const float* b1 = (const float*)d_in[9];
    const float* W2 = (const float*)d_in[10];
    const float* b2 = (const float*)d_in[11];
    float* out = (float*)d_out;

    // workspace layout (~140.2 MB)
    char* w = (char*)d_ws;
    bf16_t* xc   = (bf16_t*)(w + 0);            // [16][1024][768] compact, reused as ctxc
    bf16_t* qc   = (bf16_t*)(w + 25165824);     // reused as h1c
    bf16_t* kc   = (bf16_t*)(w + 50331648);
    bf16_t* vTc  = (bf16_t*)(w + 75497472);     // [16][768][1024] compact cols
    bf16_t* sc   = (bf16_t*)(w + 100663296);    // [16][1024][1024] bf16
    bf16_t* wqkv = (bf16_t*)(w + 134217728);    // [2304,768] = Wq|Wk|Wv
    bf16_t* w1b  = (bf16_t*)(w + 137756672);
    bf16_t* w2b  = (bf16_t*)(w + 138936320);
    float*  bqkv = (float*) (w + 140115968);    // [2304]
    int*    tok  = (int*)   (w + 140125184);    // [16][1024]
    int*    cnt  = (int*)   (w + 140190720);    // [16]
    float*  cvec = (float*) (w + 140190784);    // [768]

    dim3 blk(256);

    compact_mask<<<16, blk, 0, stream>>>(mask, tok, cnt);
    cvt_all<<<19369, blk, 0, stream>>>(x, Wq, Wk, Wv, W1, W2, bq, bk, bv, b1, b2,
                                       tok, cnt, xc, wqkv, bqkv, cvec);

    KParams p;
    p.xc = xc; p.wqkv = wqkv; p.w1b = w1b; p.w2b = w2b;
    p.bqkv = bqkv; p.b1 = b1; p.b2 = b2; p.cvec = cvec;
    p.qc = qc; p.kc = kc; p.vTc = vTc; p.sc = sc;
    p.ctxc = xc; p.h1c = qc;
    p.tok = tok; p.cnt = cnt; p.mask = mask;
    p.out = out;
    p.inv_sqrt_h = 0.036084391824351615f;  // 1/sqrt(768)

    // grid: as many co-resident blocks as occupancy allows (capped 512 = 2/CU)
    static int s_grid = 0;
    if (s_grid == 0) {
        int bpc = 0;
        if (hipOccupancyMaxActiveBlocksPerMultiprocessor(
                &bpc, (const void*)fused_chain, 512, 0) != hipSuccess || bpc < 1)
            bpc = 1;
        int g = bpc * 256;
        s_grid = g < 256 ? 256 : (g > 512 ? 512 : g);
    }

    void* args[] = { &p };
    hipLaunchCooperativeKernel((void*)fused_chain, dim3(s_grid), dim3(512),
                               args, 0, stream);
}

// Round 11
// 278.619 us; speedup vs baseline: 1.9187x; 1.9187x over previous
//
#include <hip/hip_runtime.h>
#include <hip/hip_bf16.h>

typedef __bf16 bf16_t;
typedef __bf16 bf16x8 __attribute__((ext_vector_type(8)));
typedef __bf16 bf16x4 __attribute__((ext_vector_type(4)));
typedef float f32x4 __attribute__((ext_vector_type(4)));
typedef unsigned int u32;
typedef const __attribute__((address_space(1))) u32* gptr_t;
typedef __attribute__((address_space(3))) u32* lptr_t;

static constexpr int Bb = 16, Ss = 1024, Hh = 768;

// ---- prep: mask compaction + weights->bf16 + bias pack + cvec, one launch ----
// Sections are mutually independent (the x gather moved into the QKV GEMM).
//   bx in [0,16):      compact_mask  (mask -> tok, cnt)
//   bx in [16,2896):   weight convert (Wq|Wk|Wv|W1|W2 -> bf16 slabs)
//   bx in [2896,2905): bias pack (bq|bk|bv -> bqkv fp32)
//   bx in [2905,3001): cvec = W2·relu(b1)+b2
__global__ __launch_bounds__(256) void prep_all(
    const int* __restrict__ mask,
    const float* __restrict__ w0, const float* __restrict__ w1,
    const float* __restrict__ w2, const float* __restrict__ w3,
    const float* __restrict__ w4,
    const float* __restrict__ bq, const float* __restrict__ bk,
    const float* __restrict__ bv,
    const float* __restrict__ b1, const float* __restrict__ b2,
    int* __restrict__ tok, int* __restrict__ cnt,
    bf16_t* __restrict__ wdst, float* __restrict__ bdst,
    float* __restrict__ cvec)
{
    const int bx = blockIdx.x;
    const int t = threadIdx.x;
    __shared__ int sb[256];

    if (bx < 16) {
        const int b = bx;
        const int4 m4 = *(const int4*)&mask[(b << 10) + (t << 2)];
        const int c = (m4.x != 0) + (m4.y != 0) + (m4.z != 0) + (m4.w != 0);
        sb[t] = c;
        __syncthreads();
        for (int off = 1; off < 256; off <<= 1) {
            int v = (t >= off) ? sb[t - off] : 0;
            __syncthreads();
            sb[t] += v;
            __syncthreads();
        }
        int p = sb[t] - c;  // exclusive prefix
        int* tb = tok + (b << 10);
        if (m4.x) tb[p++] = (t << 2) + 0;
        if (m4.y) tb[p++] = (t << 2) + 1;
        if (m4.z) tb[p++] = (t << 2) + 2;
        if (m4.w) tb[p++] = (t << 2) + 3;
        if (t == 255) cnt[b] = sb[255];
    } else if (bx < 2896) {
        int seg = (bx - 16) / 576;
        const float* src = seg == 0 ? w0 : seg == 1 ? w1 : seg == 2 ? w2 : seg == 3 ? w3 : w4;
        int i = ((bx - 16) % 576) * 256 + t;
        float4 v = ((const float4*)src)[i];
        bf16x4 o = { (bf16_t)v.x, (bf16_t)v.y, (bf16_t)v.z, (bf16_t)v.w };
        ((bf16x4*)(wdst + (long)seg * 589824))[i] = o;
    } else if (bx < 2905) {
        int i = (bx - 2896) * 256 + t;
        if (i < 2304)
            bdst[i] = i < 768 ? bq[i] : i < 1536 ? bk[i - 768] : bv[i - 1536];
    } else {
        // cvec: 96 blocks x 8 outputs; 32 lanes reduce one W2 row (coalesced)
        const int o = ((bx - 2905) << 3) + (t >> 5);
        const int l = t & 31;
        const float* wr = w4 + (long)o * 768;
        float acc = 0.f;
        for (int h = l; h < 768; h += 32) acc += wr[h] * fmaxf(b1[h], 0.f);
#pragma unroll
        for (int off = 16; off; off >>= 1) acc += __shfl_down(acc, off, 32);
        if (l == 0) cvec[o] = acc + b2[o];
    }
}

// ---------------- async global->LDS 16B ----------------
__device__ __forceinline__ void async_cp16(const void* g, void* l)
{
    __builtin_amdgcn_global_load_lds((gptr_t)g, (lptr_t)l, 16, 0, 0);
}

enum { EG_QKV = 0, EG_SCORE_C = 1, EG_PV = 2, EG_FFN1 = 3, EG_FFN2 = 4 };

#define SBAR __builtin_amdgcn_s_barrier()
#define VMW(n) asm volatile("s_waitcnt vmcnt(" #n ")" ::: "memory")
#define LGK0 asm volatile("s_waitcnt lgkmcnt(0)" ::: "memory")

// C = epi(A * B^T); 128x128 tile, BK=64, 8 waves (512 thr), per-wave 32x64
// (wm=wid&3, wn=wid>>2), MI=2 NI=4. Ring-2 LDS (64KB, 2 blocks/CU);
// stage(t+1) at top of iter t; VMW(0)+s_barrier per iter. LDS [128][64]
// per tile, 16B-chunk XOR swizzle chunk^=(row&7).
// A operand:
//  - EPI==EG_QKV: *** fused x gather+convert *** — reg-staged from fp32 x
//    via tok indirection (per lane: one row, 4x float4 loads -> 16 bf16 ->
//    2 swizzled ds_write_b128). Replaces the former cvt_all gather pass
//    (xc materialization) entirely. Write-XOR + read-XOR pair (rule 21).
//    Rows >= cb gather row 0 (finite). The VMW(0) before the barrier drains
//    both the A reg-loads and B glds, all issued a full compute phase early.
//  - else: glds-staged bf16 (source column pre-XOR'ed, linear LDS dest).
// B operand: glds-staged, as R9.
// DISPATCH-DENSE tile mapping (R9): block reads cnt[], maps the first tot
// raw indices onto active tiles via bijective XCD chunk swizzle + per-batch
// walk; dead blocks form the dispatch tail. PV K = ceil64(cnt).
template <int EPI, int NT>
__global__ __launch_bounds__(512) void mfma_gemm(
    const bf16_t* __restrict__ A, const bf16_t* __restrict__ B,
    const float* __restrict__ xg,
    const float* __restrict__ bias, const bf16_t* __restrict__ resid,
    const int* __restrict__ tok, const int* __restrict__ cnt,
    void* __restrict__ Cout, bf16_t* __restrict__ out2, bf16_t* __restrict__ out3,
    int K, int lda, int ldb, long sA, long sB, float scale)
{
    // ---- dispatch-dense decomposition ----
    int tot = 0;
#pragma unroll
    for (int b = 0; b < 16; b++) {
        int a = (cnt[b] + 127) >> 7;
        tot += (EPI == EG_SCORE_C) ? a * a : a * NT;
    }
    const int raw = blockIdx.x;
    if (raw >= tot) return;                      // dispatch tail, uniform exit
    const int q = tot >> 3, r = tot & 7;
    const int xcd = raw & 7, pos = raw >> 3;
    int v = xcd * q + (xcd < r ? xcd : r) + pos; // bijective [0,tot)
    int bz = 0;
    for (;;) {
        int a = (cnt[bz] + 127) >> 7;
        int t = (EPI == EG_SCORE_C) ? a * a : a * NT;
        if (v < t) break;
        v -= t; ++bz;
    }
    int mi, ni;
    if constexpr (EPI == EG_SCORE_C) {
        int a = (cnt[bz] + 127) >> 7;
        mi = v / a; ni = v - mi * a;
    } else {
        mi = v / NT; ni = v - mi * NT;
    }
    const int cb = cnt[bz];
    const int m0 = mi << 7;
    const int n0 = ni << 7;
    const int Kend = (EPI == EG_PV) ? ((cb + 63) & ~63) : K;
    const int nk = Kend >> 6;  // 64-wide K-tiles, >= 1

    constexpr int MI = 2, NI = 4;       // per-wave 32x64 of the 128x128 tile
    constexpr int TSZ = 128 * 64;       // elements per tile buffer (16 KB)

    __shared__ __align__(16) bf16_t Asl[2 * TSZ];
    __shared__ __align__(16) bf16_t Bsl[2 * TSZ];

    const int tid = threadIdx.x;
    const int wid = tid >> 6;     // 0..7
    const int lane = tid & 63;
    const int wm = wid & 3, wn = wid >> 2;

    const bf16_t* Bp = B + (long)bz * sB;

    // B staging: per glds, 64 lanes cover 8 rows x 8 chunks(16B); wave wid
    // stages rows wid*16 + q*8 + (lane>>3), q=0,1. GLOBAL column chunk
    // pre-XOR'ed with (lane>>3) = row&7 (rule 21).
    const int srow8 = lane >> 3;
    const int scg = ((lane & 7) ^ srow8) << 3;   // element offset in 64-col window
    const bf16_t* pb[2];
#pragma unroll
    for (int qq = 0; qq < 2; qq++)
        pb[qq] = Bp + (long)(n0 + (wid << 4) + (qq << 3) + srow8) * ldb + scg;
    const int wrow = wid << 4;  // wave's first staged row

    // A staging setup
    const bf16_t* pa[2] = { nullptr, nullptr };  // non-QKV glds path
    const float* xr = nullptr;                   // QKV reg-gather path
    int aw_base = 0, aw_c0 = 0, aw_c1 = 0;
    if constexpr (EPI == EG_QKV) {
        const int row = (wid << 4) + (lane >> 2);    // lane's staged row
        const int cp = (lane & 3) << 1;              // chunk pair base
        const int jrow = m0 + row;
        const int s = (jrow < cb) ? tok[(bz << 10) + jrow] : 0;
        xr = xg + (long)((bz << 10) + s) * 768 + (cp << 3);
        aw_base = row << 6;
        aw_c0 = ((cp    ) ^ (row & 7)) << 3;
        aw_c1 = ((cp + 1) ^ (row & 7)) << 3;
    } else {
        const bf16_t* Ab = A + (long)bz * sA;
#pragma unroll
        for (int qq = 0; qq < 2; qq++)
            pa[qq] = Ab + (long)(m0 + (wid << 4) + (qq << 3) + srow8) * lda + scg;
    }

    // fragment read: row=lane&15; nominal chunk kk*4+(lane>>4) XOR (row&7)
    const int arow = lane & 15;
    const int axr = lane & 7;
    const int f0 = (arow << 6) + (((lane >> 4)      ^ axr) << 3);  // kk=0
    const int f1 = (arow << 6) + ((((lane >> 4) + 4) ^ axr) << 3); // kk=1

    auto stageB = [&](int tk, int buf) {
        const long ko = (long)tk << 6;
#pragma unroll
        for (int qq = 0; qq < 2; qq++)
            async_cp16(pb[qq] + ko, &Bsl[buf * TSZ + ((wrow + (qq << 3)) << 6)]);
    };
    auto stageA_g = [&](int tk, int buf) {
        const long ko = (long)tk << 6;
#pragma unroll
        for (int qq = 0; qq < 2; qq++)
            async_cp16(pa[qq] + ko, &Asl[buf * TSZ + ((wrow + (qq << 3)) << 6)]);
    };

    float4 a4[4];
    auto ldA = [&](int tk) {
        const float4* p4 = (const float4*)(xr + ((long)tk << 6));
        a4[0] = p4[0]; a4[1] = p4[1]; a4[2] = p4[2]; a4[3] = p4[3];
    };
    auto wrA = [&](int buf) {
        bf16x8 w0 = { (bf16_t)a4[0].x, (bf16_t)a4[0].y, (bf16_t)a4[0].z, (bf16_t)a4[0].w,
                      (bf16_t)a4[1].x, (bf16_t)a4[1].y, (bf16_t)a4[1].z, (bf16_t)a4[1].w };
        bf16x8 w1 = { (bf16_t)a4[2].x, (bf16_t)a4[2].y, (bf16_t)a4[2].z, (bf16_t)a4[2].w,
                      (bf16_t)a4[3].x, (bf16_t)a4[3].y, (bf16_t)a4[3].z, (bf16_t)a4[3].w };
        bf16_t* bp = &Asl[buf * TSZ + aw_base];
        *(bf16x8*)(bp + aw_c0) = w0;
        *(bf16x8*)(bp + aw_c1) = w1;
    };

    f32x4 acc[MI][NI] = {};

    // prologue
    if constexpr (EPI == EG_QKV) {
        ldA(0); stageB(0, 0);
        __builtin_amdgcn_sched_barrier(0);
        VMW(0);
        wrA(0);
        LGK0;
        __builtin_amdgcn_sched_barrier(0);
    } else {
        stageA_g(0, 0); stageB(0, 0);
        __builtin_amdgcn_sched_barrier(0);
        VMW(0);
    }
    SBAR;

    for (int t = 0; t < nk; ++t) {
        if (t + 1 < nk) {
            if constexpr (EPI == EG_QKV) { ldA(t + 1); stageB(t + 1, (t + 1) & 1); }
            else { stageA_g(t + 1, (t + 1) & 1); stageB(t + 1, (t + 1) & 1); }
        }

        const int cba = (t & 1) * TSZ;
        bf16x8 af[MI][2], bfr[NI][2];
#pragma unroll
        for (int i = 0; i < MI; i++) {
            const int rb = cba + ((wm * MI + i) << 10);   // (wm*32+i*16)*64
            af[i][0] = *(const bf16x8*)&Asl[rb + f0];
            af[i][1] = *(const bf16x8*)&Asl[rb + f1];
        }
#pragma unroll
        for (int j = 0; j < NI; j++) {
            const int rb = cba + ((wn * NI + j) << 10);   // (wn*64+j*16)*64
            bfr[j][0] = *(const bf16x8*)&Bsl[rb + f0];
            bfr[j][1] = *(const bf16x8*)&Bsl[rb + f1];
        }
        __builtin_amdgcn_sched_barrier(0);
#pragma unroll
        for (int kk = 0; kk < 2; kk++)
#pragma unroll
            for (int i = 0; i < MI; i++)
#pragma unroll
                for (int j = 0; j < NI; j++)
                    acc[i][j] = __builtin_amdgcn_mfma_f32_16x16x32_bf16(
                        af[i][kk], bfr[j][kk], acc[i][j], 0, 0, 0);
        __builtin_amdgcn_sched_barrier(0);
        if (t + 1 < nk) {
            VMW(0);
            if constexpr (EPI == EG_QKV) {
                wrA((t + 1) & 1);
                LGK0;
                __builtin_amdgcn_sched_barrier(0);
            }
            SBAR;
        }
    }

    // epilogue — C/D per 16x16 tile: col = lane&15, row = (lane>>4)*4 + reg
    const int mb_ = m0 + wm * 32;
    const int nb_ = n0 + wn * 64;
    const int colw = lane & 15;
    const int rowq = (lane >> 4) << 2;

    if constexpr (EPI == EG_QKV) {
        float bj[NI];
#pragma unroll
        for (int j = 0; j < NI; j++) bj[j] = bias[nb_ + (j << 4) + colw];
        if (nb_ < 1536) {
            bf16_t* C = ((nb_ < 768) ? (bf16_t*)Cout : out2) + (long)bz * 786432;
            const int cbase = (nb_ < 768) ? nb_ : nb_ - 768;
#pragma unroll
            for (int i = 0; i < MI; i++)
#pragma unroll
                for (int j = 0; j < NI; j++)
#pragma unroll
                    for (int r2 = 0; r2 < 4; r2++) {
                        int row = mb_ + (i << 4) + rowq + r2;
                        int col = cbase + (j << 4) + colw;
                        C[(long)row * Hh + col] = (bf16_t)fmaxf(acc[i][j][r2] + bj[j], 0.f);
                    }
        } else {
            bf16_t* C = out3 + (long)bz * 786432;  // vTc[b][h][jc]
#pragma unroll
            for (int i = 0; i < MI; i++) {
                const int jc0 = mb_ + (i << 4) + rowq;
#pragma unroll
                for (int j = 0; j < NI; j++) {
                    const int col = nb_ - 1536 + (j << 4) + colw;
                    bf16x4 o = { (bf16_t)(acc[i][j][0] + bj[j]), (bf16_t)(acc[i][j][1] + bj[j]),
                                 (bf16_t)(acc[i][j][2] + bj[j]), (bf16_t)(acc[i][j][3] + bj[j]) };
                    *(bf16x4*)&C[(long)col * 1024 + jc0] = o;
                }
            }
        }
    } else if constexpr (EPI == EG_SCORE_C) {
        // computed T = k·q^T (rows=keys); store S = T^T, no mask (all tokens valid)
        bf16_t* C = (bf16_t*)Cout + (long)bz * 1048576;
#pragma unroll
        for (int i = 0; i < MI; i++) {
            const int kbase = mb_ + (i << 4) + rowq;
#pragma unroll
            for (int j = 0; j < NI; j++) {
                const int qrow = nb_ + (j << 4) + colw;
                bf16x4 o = { (bf16_t)(acc[i][j][0] * scale), (bf16_t)(acc[i][j][1] * scale),
                             (bf16_t)(acc[i][j][2] * scale), (bf16_t)(acc[i][j][3] * scale) };
                *(bf16x4*)&C[(long)qrow * 1024 + kbase] = o;
            }
        }
    } else if constexpr (EPI == EG_FFN2) {
        float* outp = (float*)Cout;
        const bf16_t* crow = resid + (long)bz * 786432;
        const int* tb = tok + (bz << 10);
        float bj[NI];
#pragma unroll
        for (int j = 0; j < NI; j++) bj[j] = bias[nb_ + (j << 4) + colw];
#pragma unroll
        for (int i = 0; i < MI; i++)
#pragma unroll
            for (int r2 = 0; r2 < 4; r2++) {
                const int jq = mb_ + (i << 4) + rowq + r2;
                if (jq < cb) {
                    const int s = tb[jq];
                    float* orow = outp + ((long)((bz << 10) + s)) * 768;
                    const bf16_t* cr = crow + (long)jq * 768;
#pragma unroll
                    for (int j = 0; j < NI; j++) {
                        const int col = nb_ + (j << 4) + colw;
                        orow[col] = acc[i][j][r2] + bj[j] + (float)cr[col];
                    }
                }
            }
    } else {
        // EG_PV (plain bf16) / EG_FFN1 (relu+bias bf16), compact per-batch
        bf16_t* C = (bf16_t*)Cout + (long)bz * 786432;
        float bj[NI];
#pragma unroll
        for (int j = 0; j < NI; j++) bj[j] = 0.f;
        if constexpr (EPI == EG_FFN1) {
#pragma unroll
            for (int j = 0; j < NI; j++) bj[j] = bias[nb_ + (j << 4) + colw];
        }
#pragma unroll
        for (int i = 0; i < MI; i++)
#pragma unroll
            for (int j = 0; j < NI; j++)
#pragma unroll
                for (int r2 = 0; r2 < 4; r2++) {
                    int row = mb_ + (i << 4) + rowq + r2;
                    int col = nb_ + (j << 4) + colw;
                    float val = acc[i][j][r2] + bj[j];
                    if constexpr (EPI == EG_FFN1) val = fmaxf(val, 0.f);
                    C[(long)row * Hh + col] = (bf16_t)val;
                }
    }
}

// ---- z=0: softmax over compact keys (validity = col < cnt, no mask loads)
// ---- z=1: fill masked output rows with cvec (disjoint from FFN2's rows)
__global__ __launch_bounds__(256) void softmax_rows(
    bf16_t* __restrict__ S_, const int* __restrict__ cnt,
    const int* __restrict__ mask, const float* __restrict__ cvec,
    float* __restrict__ out)
{
    const int b = blockIdx.y;
    const int t = threadIdx.x;

    if (blockIdx.z == 1) {
        const int s = blockIdx.x;
        if (t >= 192 || mask[(b << 10) + s]) return;
        float4 v = ((const float4*)cvec)[t];
        ((float4*)(out + ((long)((b << 10) + s)) * 768))[t] = v;
        return;
    }

    const int jq = blockIdx.x;
    const int cb = cnt[b];
    if (jq >= cb) return;
    bf16_t* p = S_ + (((long)(b << 10)) + jq) * 1024;
    const int t0 = t << 2;

    bf16x4 v4 = *(const bf16x4*)&p[t0];
    float v0 = (t0 + 0 < cb) ? (float)v4[0] : -1e30f;
    float v1 = (t0 + 1 < cb) ? (float)v4[1] : -1e30f;
    float v2 = (t0 + 2 < cb) ? (float)v4[2] : -1e30f;
    float v3 = (t0 + 3 < cb) ? (float)v4[3] : -1e30f;

    float mx = fmaxf(fmaxf(v0, v1), fmaxf(v2, v3));
#pragma unroll
    for (int off = 32; off; off >>= 1) mx = fmaxf(mx, __shfl_down(mx, off, 64));
    __shared__ float redm[4], reds[4];
    if ((t & 63) == 0) redm[t >> 6] = mx;
    __syncthreads();
    mx = fmaxf(fmaxf(redm[0], redm[1]), fmaxf(redm[2], redm[3]));

    // invalid lanes: exp(-1e30 - mx) underflows to exactly 0
    float e0 = __expf(v0 - mx), e1 = __expf(v1 - mx);
    float e2 = __expf(v2 - mx), e3 = __expf(v3 - mx);
    float sm = e0 + e1 + e2 + e3;
#pragma unroll
    for (int off = 32; off; off >>= 1) sm += __shfl_down(sm, off, 64);
    if ((t & 63) == 0) reds[t >> 6] = sm;
    __syncthreads();
    sm = reds[0] + reds[1] + reds[2] + reds[3];

    const float inv = 1.f / sm;
    bf16x4 o = { (bf16_t)(e0 * inv), (bf16_t)(e1 * inv),
                 (bf16_t)(e2 * inv), (bf16_t)(e3 * inv) };
    *(bf16x4*)&p[t0] = o;
}

extern "C" void kernel_launch(void* const* d_in, const int* in_sizes, int n_in,
                              void* d_out, int out_size, void* d_ws, size_t ws_size,
                              hipStream_t stream)
{
    const float* x  = (const float*)d_in[0];
    const int* mask = (const int*)d_in[1];
    const float* Wq = (const float*)d_in[2];
    const float* bq = (const float*)d_in[3];
    const float* Wk = (const float*)d_in[4];
    const float* bk = (const float*)d_in[5];
    const float* Wv = (const float*)d_in[6];
    const float* bv = (const float*)d_in[7];
    const float* W1 = (const float*)d_in[8];
    const float* b1 = (const float*)d_in[9];
    const float* W2 = (const float*)d_in[10];
    const float* b2 = (const float*)d_in[11];
    float* out = (float*)d_out;

    // workspace layout (~140.2 MB)
    char* w = (char*)d_ws;
    bf16_t* ctxc = (bf16_t*)(w + 0);            // [16][1024][768] compact (PV out)
    bf16_t* qc   = (bf16_t*)(w + 25165824);     // reused as h1c
    bf16_t* kc   = (bf16_t*)(w + 50331648);
    bf16_t* vTc  = (bf16_t*)(w + 75497472);     // [16][768][1024] compact cols
    bf16_t* sc   = (bf16_t*)(w + 100663296);    // [16][1024][1024] bf16
    bf16_t* wqkv = (bf16_t*)(w + 134217728);    // [2304,768] = Wq|Wk|Wv
    bf16_t* w1b  = (bf16_t*)(w + 137756672);
    bf16_t* w2b  = (bf16_t*)(w + 138936320);
    float*  bqkv = (float*) (w + 140115968);    // [2304]
    int*    tok  = (int*)   (w + 140125184);    // [16][1024]
    int*    cnt  = (int*)   (w + 140190720);    // [16]
    float*  cvec = (float*) (w + 140190784);    // [768]
    bf16_t* h1c  = qc;

    const float inv_sqrt_h = 0.036084391824351615f; // 1/sqrt(768)
    dim3 blk(256);
    dim3 blk8(512);

    // single prep launch: compact + weight convert + bias pack + cvec
    prep_all<<<3001, blk, 0, stream>>>(mask, Wq, Wk, Wv, W1, W2,
                                       bq, bk, bv, b1, b2,
                                       tok, cnt, wqkv, bqkv, cvec);

    // qc|kc|vTc = epi(x[tok]·[Wq|Wk|Wv]^T + bqkv)  — x gather+convert fused
    mfma_gemm<EG_QKV, 18><<<2304, blk8, 0, stream>>>(
        nullptr, wqkv, x, bqkv, nullptr, tok, cnt, qc, kc, vTc,
        768, 768, 768, 0, 0, 1.f);

    // sc[jq][jk] = (kc·qc^T)^T * scale  (both dims compact)
    mfma_gemm<EG_SCORE_C, 1><<<1024, blk8, 0, stream>>>(
        kc, qc, nullptr, nullptr, nullptr, tok, cnt, sc, nullptr, nullptr,
        768, 768, 768, 786432, 786432, inv_sqrt_h);

    // z=0: softmax over valid keys in place; z=1: masked out rows = cvec
    softmax_rows<<<dim3(1024, 16, 2), blk, 0, stream>>>(sc, cnt, mask, cvec, out);

    // ctxc = sc · vTc^T   (K = ceil64(cnt) per batch)
    mfma_gemm<EG_PV, 6><<<768, blk8, 0, stream>>>(
        sc, vTc, nullptr, nullptr, nullptr, tok, cnt, ctxc, nullptr, nullptr,
        0, 1024, 1024, 1048576, 786432, 1.f);

    // h1c = relu(ctxc · W1^T + b1)
    mfma_gemm<EG_FFN1, 6><<<768, blk8, 0, stream>>>(
        ctxc, w1b, nullptr, b1, nullptr, tok, cnt, h1c, nullptr, nullptr,
        768, 768, 768, 786432, 0, 1.f);

    // out[b][tok[jq]] = h1c · W2^T + b2 + ctxc   (scatter, fp32)
    mfma_gemm<EG_FFN2, 6><<<768, blk8, 0, stream>>>(
        h1c, w2b, nullptr, b2, ctxc, tok, cnt, out, nullptr, nullptr,
        768, 768, 768, 786432, 0, 1.f);
}